// Round 6
// baseline (128.375 us; speedup 1.0000x reference)
//
#include <hip/hip_runtime.h>

constexpr int Bn = 32;
constexpr int Cn = 256;
constexpr int Nn = 1024;

constexpr float C2 = 2.8853900817779268f;  // 2/ln2
constexpr float K1 = 1.4426950408889634f;  // 1/ln2

typedef __bf16 v8bf  __attribute__((ext_vector_type(8)));
typedef float  v16f  __attribute__((ext_vector_type(16)));

// hbf layout (IDENTICAL to round-3 green kernel): [b][nt32][c][32n] bf16.
// nt32 block = 16384 B, c-row = 64 B holding n = nt32*32 + [0,32) as four
// 16-B groups; group g (= (n_local>>3)) stored at position (g ^ (c&3));
// within group: byte (n&7)*2.

__device__ __forceinline__ void async16(const void* g, void* l) {
    __builtin_amdgcn_global_load_lds(
        (const __attribute__((address_space(1))) unsigned int*)g,
        (__attribute__((address_space(3))) unsigned int*)l, 16, 0, 0);
}

// ---------------------------------------------------------------------------
// Prep (NEW vs round 3 — only change this round): dots -> pa=e^{2a}, q=e^{2k};
// h fp32 -> hbf bf16 in the round-3 layout, but via LDS transpose + 16-B
// stores instead of 8.4M scalar 2-B stores.
// Block = (b, 64-n chunk), 256 thr. Per 64-c chunk: load+dot+stash fp32 tile,
// barrier, emit phase: thread (w,l) packs 2 XOR-placed 16-B groups.
// ---------------------------------------------------------------------------
__global__ __launch_bounds__(256) void prep_kernel(
    const float* __restrict__ h,
    const float* __restrict__ w1, const float* __restrict__ w1b,
    const float* __restrict__ w2, const float* __restrict__ w2b,
    float* __restrict__ pa_g, float* __restrict__ q_g,
    unsigned char* __restrict__ hbf)
{
    int blk = blockIdx.x;
    int xcd = blk & 7, idx = blk >> 3;
    int b   = xcd * 4 + (idx >> 4);
    int n0  = (idx & 15) * 64;
    int t = threadIdx.x, w = t >> 6, l = t & 63;

    __shared__ float lds_t[64][68];          // [c-within-chunk][n-within-64], pad
    __shared__ float p1[4][64], p2[4][64];

    const float* hb = h + (size_t)b * Cn * Nn + n0;
    float s1 = 0.f, s2 = 0.f;

    // emit-phase invariants: this thread owns c = chunk*64 + l,
    // nt32 = n0/32 + (w>>1), groups g in {2*(w&1), 2*(w&1)+1}
    int nt32  = (n0 >> 5) + (w >> 1);
    int gbase = (w & 1) * 2;
    unsigned char* nt_base = hbf + (size_t)(b * 32 + nt32) * 16384;

    for (int chunk = 0; chunk < 4; ++chunk) {
        if (chunk) __syncthreads();          // emit readers of prev chunk done
#pragma unroll 4
        for (int ci = 0; ci < 16; ++ci) {
            int c = chunk * 64 + w * 16 + ci;
            float v = hb[(size_t)c * Nn + l];        // coalesced: lane = n
            s1 = fmaf(v, w1[c], s1);
            s2 = fmaf(v, w2[c], s2);
            lds_t[w * 16 + ci][l] = v;
        }
        __syncthreads();
        // emit: c = chunk*64 + l; two 16-B groups of nt32
        int c = chunk * 64 + l;
        unsigned char* crow = nt_base + c * 64;
#pragma unroll
        for (int g2 = 0; g2 < 2; ++g2) {
            int g = gbase + g2;
            int col = (w >> 1) * 32 + g * 8;         // n - n0
            float4 va = *(const float4*)&lds_t[l][col];
            float4 vb = *(const float4*)&lds_t[l][col + 4];
            union { __bf16 bx[8]; uint4 u4; } pk;
            pk.bx[0] = (__bf16)va.x; pk.bx[1] = (__bf16)va.y;
            pk.bx[2] = (__bf16)va.z; pk.bx[3] = (__bf16)va.w;
            pk.bx[4] = (__bf16)vb.x; pk.bx[5] = (__bf16)vb.y;
            pk.bx[6] = (__bf16)vb.z; pk.bx[7] = (__bf16)vb.w;
            *(uint4*)(crow + ((g ^ (c & 3)) << 4)) = pk.u4;
        }
    }

    p1[w][l] = s1;
    p2[w][l] = s2;
    __syncthreads();
    if (t < 64) {
        float a = p1[0][t] + p1[1][t] + p1[2][t] + p1[3][t] + w1b[0];
        float k = p2[0][t] + p2[1][t] + p2[2][t] + p2[3][t] + w2b[0];
        pa_g[b * Nn + n0 + t] = exp2f(C2 * a);
        q_g [b * Nn + n0 + t] = exp2f(C2 * k);
    }
}

// ---------------------------------------------------------------------------
// Ctx: BYTE-IDENTICAL to the round-3 green kernel. Do not touch this round.
// ---------------------------------------------------------------------------
constexpr int EST_OFF  = 32768;           // Bl [2][16384) at 0
constexpr int QS_OFF   = 65792;           // comb[64][257] f32 aliases [0,65792)
constexpr int SP_OFF   = 69888;
constexpr int SINV_OFF = 71936;
constexpr int CTX_SMEM = 72192;

__global__ __launch_bounds__(512, 2) void ctx_kernel(
    const unsigned char* __restrict__ hbf,
    const float* __restrict__ pa_g, const float* __restrict__ q_g,
    float* __restrict__ out)
{
    __shared__ alignas(16) unsigned char smem[CTX_SMEM];
    float* qs           = (float*)(smem + QS_OFF);
    float (*Sp)[64]     = (float(*)[64])(smem + SP_OFF);
    float* Sinv         = (float*)(smem + SINV_OFF);
    float (*comb)[257]  = (float(*)[257])smem;

    int blk = blockIdx.x;
    int xcd = blk & 7, slot = blk >> 3;
    int b   = xcd * 4 + (slot >> 4);
    int i0  = (slot & 15) * 64;

    int t = threadIdx.x, w = t >> 6, l = t & 63;
    int lm = l & 31, lh = l >> 5;
    int cq = w & 3, wq = w >> 2;

    const unsigned char* hbf_b = hbf + (size_t)b * 524288;

    for (int i = t; i < Nn; i += 512) qs[i] = q_g[b * Nn + i];
    float pav = pa_g[b * Nn + i0 + l];          // gen row = l

    v16f acc[2][2];
#pragma unroll
    for (int x = 0; x < 2; ++x)
#pragma unroll
        for (int y = 0; y < 2; ++y)
#pragma unroll
            for (int r = 0; r < 16; ++r) acc[x][y][r] = 0.f;
    float Spart = 0.f;

    unsigned char* estw = smem + EST_OFF + l * 128 + ((w ^ (l & 7)) << 4);

    for (int tt = 0; tt < 16; ++tt) {
        __syncthreads();                         // prev tile consumed (covers qs on tt=0)
        // ---- async stage B: both K-half 16KB slices, lane-linear ----
#pragma unroll
        for (int p = 0; p < 4; ++p) {
            int id = p * 8 + w;
            int hh = id >> 4, off = (id & 15) << 10;
            const unsigned char* src = hbf_b + (((hh << 4) + tt) << 14) + off + (l << 4);
            async16(src, smem + (hh << 14) + off);
        }
        // ---- generate E (overlaps DMA): wave w -> half w>>2, oct w&3 ----
        {
            int qb = (w >> 2) * 512 + tt * 32 + (w & 3) * 8;
            float4 q0 = *(const float4*)&qs[qb];
            float4 q1 = *(const float4*)&qs[qb + 4];
            float qv[8] = {q0.x, q0.y, q0.z, q0.w, q1.x, q1.y, q1.z, q1.w};
            v8bf ev;
#pragma unroll
            for (int j = 0; j < 8; ++j) {
                float z = pav * qv[j];                       // e^{2(a+k)}
                float r = __builtin_amdgcn_rcpf(1.f + z);
                float e = exp2f(fmaf(r, -2.f * K1, K1));     // e^{tanh}
                __bf16 eb = (__bf16)e;
                ev[j] = eb;
                Spart += (float)eb;
            }
            *(v8bf*)estw = ev;
        }
        __syncthreads();                         // DMA drained + Est ready
        // ---- MFMA phase: 8 b128 reads, 8 MFMA per wave ----
#pragma unroll
        for (int ks = 0; ks < 2; ++ks) {
            int gA = ((wq << 2) + (ks << 1) + lh) ^ (lm & 7);
            v8bf a0 = *(const v8bf*)(smem + EST_OFF + lm * 128        + (gA << 4));
            v8bf a1 = *(const v8bf*)(smem + EST_OFF + (32 + lm) * 128 + (gA << 4));
            int gB = ((ks << 1) + lh) ^ (lm & 3);
            const unsigned char* bB = smem + (wq << 14) + (cq * 64 + lm) * 64;
            v8bf b0 = *(const v8bf*)(bB +        (gB << 4));
            v8bf b1 = *(const v8bf*)(bB + 2048 + (gB << 4));   // +32 c rows
            acc[0][0] = __builtin_amdgcn_mfma_f32_32x32x16_bf16(a0, b0, acc[0][0], 0, 0, 0);
            acc[0][1] = __builtin_amdgcn_mfma_f32_32x32x16_bf16(a0, b1, acc[0][1], 0, 0, 0);
            acc[1][0] = __builtin_amdgcn_mfma_f32_32x32x16_bf16(a1, b0, acc[1][0], 0, 0, 0);
            acc[1][1] = __builtin_amdgcn_mfma_f32_32x32x16_bf16(a1, b1, acc[1][1], 0, 0, 0);
        }
    }

    // ---- epilogue ----
    Sp[w][l] = Spart;
    __syncthreads();                             // also: Bl/Est dead -> comb alias safe
    if (t < 64) {
        float S = 0.f;
#pragma unroll
        for (int ww = 0; ww < 8; ++ww) S += Sp[ww][t];
        Sinv[t] = 1.f / S;
    }
    if (wq == 1) {
#pragma unroll
        for (int x = 0; x < 2; ++x)
#pragma unroll
            for (int y = 0; y < 2; ++y)
#pragma unroll
                for (int r = 0; r < 16; ++r) {
                    int rl = (r & 3) + 8 * (r >> 2) + 4 * lh;
                    comb[x * 32 + rl][cq * 64 + y * 32 + lm] = acc[x][y][r];
                }
    }
    __syncthreads();
    if (wq == 0) {
#pragma unroll
        for (int x = 0; x < 2; ++x)
#pragma unroll
            for (int y = 0; y < 2; ++y)
#pragma unroll
                for (int r = 0; r < 16; ++r) {
                    int rl  = (r & 3) + 8 * (r >> 2) + 4 * lh;
                    int row = x * 32 + rl;
                    int col = cq * 64 + y * 32 + lm;
                    float v = (acc[x][y][r] + comb[row][col]) * Sinv[row];
                    v = (v >= 0.f) ? v : 0.2f * v;
                    comb[row][col] = v;
                }
    }
    __syncthreads();
    // ---- coalesced store out[b][c][i0..i0+63] ----
    float* ob = out + (size_t)b * Cn * Nn + i0;
#pragma unroll
    for (int p = 0; p < 8; ++p) {
        int slot = t + (p << 9);
        int c    = slot >> 4;
        int i4   = (slot & 15) << 2;
        float4 o;
        o.x = comb[i4 + 0][c];
        o.y = comb[i4 + 1][c];
        o.z = comb[i4 + 2][c];
        o.w = comb[i4 + 3][c];
        *(float4*)(ob + (size_t)c * Nn + i4) = o;
    }
}

// ---------------------------------------------------------------------------
extern "C" void kernel_launch(void* const* d_in, const int* in_sizes, int n_in,
                              void* d_out, int out_size, void* d_ws, size_t ws_size,
                              hipStream_t stream) {
    const float* h   = (const float*)d_in[0];
    const float* w1w = (const float*)d_in[1];
    const float* w1b = (const float*)d_in[2];
    const float* w2w = (const float*)d_in[3];
    const float* w2b = (const float*)d_in[4];
    float* out = (float*)d_out;

    float* pa_ws = (float*)d_ws;                              // [0, 128K)
    float* q_ws  = pa_ws + Bn * Nn;                           // [128K, 256K)
    unsigned char* hbf = (unsigned char*)d_ws + 262144;       // 16 MB blocked bf16

    prep_kernel<<<512, 256, 0, stream>>>(h, w1w, w1b, w2w, w2b, pa_ws, q_ws, hbf);
    ctx_kernel <<<512, 512, 0, stream>>>(hbf, pa_ws, q_ws, out);
}

// Round 7
// 121.445 us; speedup vs baseline: 1.0571x; 1.0571x over previous
//
#include <hip/hip_runtime.h>

constexpr int Bn = 32;
constexpr int Cn = 256;
constexpr int Nn = 1024;

constexpr float C2 = 2.8853900817779268f;  // 2/ln2
constexpr float K1 = 1.4426950408889634f;  // 1/ln2

typedef __bf16 v8bf  __attribute__((ext_vector_type(8)));
typedef float  v16f  __attribute__((ext_vector_type(16)));

// hbf layout (round-3/6 green): [b][nt32][c][32n] bf16.
// nt32 block = 16384 B, c-row = 64 B holding n = nt32*32 + [0,32) as four
// 16-B groups; group g (= n_local>>3) stored at position (g ^ (c&3));
// within group: byte (n&7)*2.

// ---------------------------------------------------------------------------
// Prep: BYTE-IDENTICAL to round-6 green. dots -> pa=e^{2a}, q=e^{2k};
// h fp32 -> hbf bf16 via LDS transpose + 16-B stores.
// ---------------------------------------------------------------------------
__global__ __launch_bounds__(256) void prep_kernel(
    const float* __restrict__ h,
    const float* __restrict__ w1, const float* __restrict__ w1b,
    const float* __restrict__ w2, const float* __restrict__ w2b,
    float* __restrict__ pa_g, float* __restrict__ q_g,
    unsigned char* __restrict__ hbf)
{
    int blk = blockIdx.x;
    int xcd = blk & 7, idx = blk >> 3;
    int b   = xcd * 4 + (idx >> 4);
    int n0  = (idx & 15) * 64;
    int t = threadIdx.x, w = t >> 6, l = t & 63;

    __shared__ float lds_t[64][68];          // [c-within-chunk][n-within-64], pad
    __shared__ float p1[4][64], p2[4][64];

    const float* hb = h + (size_t)b * Cn * Nn + n0;
    float s1 = 0.f, s2 = 0.f;

    int nt32  = (n0 >> 5) + (w >> 1);
    int gbase = (w & 1) * 2;
    unsigned char* nt_base = hbf + (size_t)(b * 32 + nt32) * 16384;

    for (int chunk = 0; chunk < 4; ++chunk) {
        if (chunk) __syncthreads();          // emit readers of prev chunk done
#pragma unroll 4
        for (int ci = 0; ci < 16; ++ci) {
            int c = chunk * 64 + w * 16 + ci;
            float v = hb[(size_t)c * Nn + l];        // coalesced: lane = n
            s1 = fmaf(v, w1[c], s1);
            s2 = fmaf(v, w2[c], s2);
            lds_t[w * 16 + ci][l] = v;
        }
        __syncthreads();
        int c = chunk * 64 + l;
        unsigned char* crow = nt_base + c * 64;
#pragma unroll
        for (int g2 = 0; g2 < 2; ++g2) {
            int g = gbase + g2;
            int col = (w >> 1) * 32 + g * 8;         // n - n0
            float4 va = *(const float4*)&lds_t[l][col];
            float4 vb = *(const float4*)&lds_t[l][col + 4];
            union { __bf16 bx[8]; uint4 u4; } pk;
            pk.bx[0] = (__bf16)va.x; pk.bx[1] = (__bf16)va.y;
            pk.bx[2] = (__bf16)va.z; pk.bx[3] = (__bf16)va.w;
            pk.bx[4] = (__bf16)vb.x; pk.bx[5] = (__bf16)vb.y;
            pk.bx[6] = (__bf16)vb.z; pk.bx[7] = (__bf16)vb.w;
            *(uint4*)(crow + ((g ^ (c & 3)) << 4)) = pk.u4;
        }
    }

    p1[w][l] = s1;
    p2[w][l] = s2;
    __syncthreads();
    if (t < 64) {
        float a = p1[0][t] + p1[1][t] + p1[2][t] + p1[3][t] + w1b[0];
        float k = p2[0][t] + p2[1][t] + p2[2][t] + p2[3][t] + w2b[0];
        pa_g[b * Nn + n0 + t] = exp2f(C2 * a);
        q_g [b * Nn + n0 + t] = exp2f(C2 * k);
    }
}

// ---------------------------------------------------------------------------
// Ctx: green round-3 skeleton (2 barriers/tile, est gen + XOR layout, epilogue
// identical). ONE change: B-fragments are loaded from hbf (global, L2-hot)
// straight into VGPRs instead of DMA->LDS->ds_read. No async DMA remains.
// ---------------------------------------------------------------------------
constexpr int EST_OFF  = 0;               // est[64][128B] = 8192
constexpr int QS_OFF   = 8192;            // qs 4096; comb[64][257] aliases [0,65792)
constexpr int SP_OFF   = 65792;
constexpr int SINV_OFF = 67840;
constexpr int CTX_SMEM = 68096;

__global__ __launch_bounds__(512, 4) void ctx_kernel(
    const unsigned char* __restrict__ hbf,
    const float* __restrict__ pa_g, const float* __restrict__ q_g,
    float* __restrict__ out)
{
    __shared__ alignas(16) unsigned char smem[CTX_SMEM];
    float* qs           = (float*)(smem + QS_OFF);
    float (*Sp)[64]     = (float(*)[64])(smem + SP_OFF);
    float* Sinv         = (float*)(smem + SINV_OFF);
    float (*comb)[257]  = (float(*)[257])smem;

    int blk = blockIdx.x;
    int xcd = blk & 7, slot = blk >> 3;
    int b   = xcd * 4 + (slot >> 4);
    int i0  = (slot & 15) * 64;

    int t = threadIdx.x, w = t >> 6, l = t & 63;
    int lm = l & 31, lh = l >> 5;
    int cq = w & 3, wq = w >> 2;

    const unsigned char* hbf_b = hbf + (size_t)b * 524288;

    for (int i = t; i < Nn; i += 512) qs[i] = q_g[b * Nn + i];
    float pav = pa_g[b * Nn + i0 + l];          // gen row = l

    v16f acc[2][2];
#pragma unroll
    for (int x = 0; x < 2; ++x)
#pragma unroll
        for (int y = 0; y < 2; ++y)
#pragma unroll
            for (int r = 0; r < 16; ++r) acc[x][y][r] = 0.f;
    float Spart = 0.f;

    unsigned char* estw = smem + EST_OFF + l * 128 + ((w ^ (l & 7)) << 4);

    // loop-invariant B-frag byte offsets within an nt32 block:
    // c = cq*64 + lm (s=1 adds +2048 = 32 c-rows); group g = ks*2 + lh at
    // physical position (g ^ (c&3)).
    int cB   = cq * 64 + lm;
    int m4   = cB & 3;
    int off0 = cB * 64 + ((lh ^ m4) << 4);          // ks = 0
    int off1 = cB * 64 + (((2 + lh) ^ m4) << 4);    // ks = 1

    for (int tt = 0; tt < 16; ++tt) {
        __syncthreads();                 // prev est consumed (tt=0: qs ready)
        // ---- B-frags for this tile: 4 x 16B global loads (L2-hot),
        //      issued before gen so they land under gen + barrier ----
        const unsigned char* pt = hbf_b + (size_t)((wq << 4) + tt) * 16384;
        v8bf b00 = *(const v8bf*)(pt + off0);
        v8bf b01 = *(const v8bf*)(pt + off0 + 2048);
        v8bf b10 = *(const v8bf*)(pt + off1);
        v8bf b11 = *(const v8bf*)(pt + off1 + 2048);
        // ---- generate E (identical to green) ----
        {
            int qb = wq * 512 + tt * 32 + cq * 8;
            float4 q0 = *(const float4*)&qs[qb];
            float4 q1 = *(const float4*)&qs[qb + 4];
            float qv[8] = {q0.x, q0.y, q0.z, q0.w, q1.x, q1.y, q1.z, q1.w};
            v8bf ev;
#pragma unroll
            for (int j = 0; j < 8; ++j) {
                float z = pav * qv[j];                       // e^{2(a+k)}
                float r = __builtin_amdgcn_rcpf(1.f + z);
                float e = exp2f(fmaf(r, -2.f * K1, K1));     // e^{tanh}
                __bf16 eb = (__bf16)e;
                ev[j] = eb;
                Spart += (float)eb;
            }
            *(v8bf*)estw = ev;
        }
        __syncthreads();                 // est published
        // ---- MFMA phase: 4 A ds_reads + 8 MFMA ----
#pragma unroll
        for (int ks = 0; ks < 2; ++ks) {
            int gA = ((wq << 2) + (ks << 1) + lh) ^ (lm & 7);
            v8bf a0 = *(const v8bf*)(smem + EST_OFF + lm * 128        + (gA << 4));
            v8bf a1 = *(const v8bf*)(smem + EST_OFF + (32 + lm) * 128 + (gA << 4));
            v8bf b0 = ks ? b10 : b00;
            v8bf b1 = ks ? b11 : b01;
            acc[0][0] = __builtin_amdgcn_mfma_f32_32x32x16_bf16(a0, b0, acc[0][0], 0, 0, 0);
            acc[0][1] = __builtin_amdgcn_mfma_f32_32x32x16_bf16(a0, b1, acc[0][1], 0, 0, 0);
            acc[1][0] = __builtin_amdgcn_mfma_f32_32x32x16_bf16(a1, b0, acc[1][0], 0, 0, 0);
            acc[1][1] = __builtin_amdgcn_mfma_f32_32x32x16_bf16(a1, b1, acc[1][1], 0, 0, 0);
        }
    }

    // ---- epilogue (identical to green) ----
    Sp[w][l] = Spart;
    __syncthreads();                     // est/qs dead -> comb alias safe
    if (t < 64) {
        float S = 0.f;
#pragma unroll
        for (int ww = 0; ww < 8; ++ww) S += Sp[ww][t];
        Sinv[t] = 1.f / S;
    }
    if (wq == 1) {
#pragma unroll
        for (int x = 0; x < 2; ++x)
#pragma unroll
            for (int y = 0; y < 2; ++y)
#pragma unroll
                for (int r = 0; r < 16; ++r) {
                    int rl = (r & 3) + 8 * (r >> 2) + 4 * lh;
                    comb[x * 32 + rl][cq * 64 + y * 32 + lm] = acc[x][y][r];
                }
    }
    __syncthreads();
    if (wq == 0) {
#pragma unroll
        for (int x = 0; x < 2; ++x)
#pragma unroll
            for (int y = 0; y < 2; ++y)
#pragma unroll
                for (int r = 0; r < 16; ++r) {
                    int rl  = (r & 3) + 8 * (r >> 2) + 4 * lh;
                    int row = x * 32 + rl;
                    int col = cq * 64 + y * 32 + lm;
                    float v = (acc[x][y][r] + comb[row][col]) * Sinv[row];
                    v = (v >= 0.f) ? v : 0.2f * v;
                    comb[row][col] = v;
                }
    }
    __syncthreads();
    float* ob = out + (size_t)b * Cn * Nn + i0;
#pragma unroll
    for (int p = 0; p < 8; ++p) {
        int slot = t + (p << 9);
        int c    = slot >> 4;
        int i4   = (slot & 15) << 2;
        float4 o;
        o.x = comb[i4 + 0][c];
        o.y = comb[i4 + 1][c];
        o.z = comb[i4 + 2][c];
        o.w = comb[i4 + 3][c];
        *(float4*)(ob + (size_t)c * Nn + i4) = o;
    }
}

// ---------------------------------------------------------------------------
extern "C" void kernel_launch(void* const* d_in, const int* in_sizes, int n_in,
                              void* d_out, int out_size, void* d_ws, size_t ws_size,
                              hipStream_t stream) {
    const float* h   = (const float*)d_in[0];
    const float* w1w = (const float*)d_in[1];
    const float* w1b = (const float*)d_in[2];
    const float* w2w = (const float*)d_in[3];
    const float* w2b = (const float*)d_in[4];
    float* out = (float*)d_out;

    float* pa_ws = (float*)d_ws;                              // [0, 128K)
    float* q_ws  = pa_ws + Bn * Nn;                           // [128K, 256K)
    unsigned char* hbf = (unsigned char*)d_ws + 262144;       // 16 MB blocked bf16

    prep_kernel<<<512, 256, 0, stream>>>(h, w1w, w1b, w2w, w2b, pa_ws, q_ws, hbf);
    ctx_kernel <<<512, 512, 0, stream>>>(hbf, pa_ws, q_ws, out);
}